// Round 3
// baseline (264.894 us; speedup 1.0000x reference)
//
#include <hip/hip_runtime.h>
#include <hip/hip_fp16.h>

#define DIM   160
#define DIM2  25600
#define TY    16
#define TX    32
#define TZ    20
#define HY    22            // TY + 6
#define HX    38            // TX + 6
#define HXP   40            // padded row (float4-aligned)
#define NSL   26            // TZ + 6
#define NSITE (HY * HX)     // 836
#define COFF  (TY * HXP)    // 640
#define NVOX_D 16384000.0

#define W0 0.03663285f
#define W1 0.11128076f
#define W2 0.21674532f
#define W3 0.27068213f

__global__ void ssim_zero_acc(double* acc) {
    if (threadIdx.x == 0 && blockIdx.x == 0) acc[0] = 0.0;
}

__global__ __launch_bounds__(256, 4) void ssim_main(const float* __restrict__ P,
                                                    const float* __restrict__ T,
                                                    double* __restrict__ acc) {
    const float Wk[7] = {W0, W1, W2, W3, W2, W1, W0};

    __shared__ float sP[HY * HXP];
    __shared__ float sT[HY * HXP];
    __shared__ float yc[5 * COFF];
    __shared__ float red[4];

    const int tid = threadIdx.x;
    int bid = blockIdx.x;
    int b  = bid / 400;  int r  = bid - b * 400;   // 8 zc * 10 ty * 5 tx
    int zc = r / 50;     int r2 = r - zc * 50;
    int ty = r2 / 5;     int tx = r2 - ty * 5;

    const int base = b * (DIM * DIM * DIM);
    const int z0 = zc * TZ, y0 = ty * TY - 3, x0 = tx * TX - 3;

    // ---- per-thread load-site precompute (4 slots, u = tid + 256k) ----
    int  gofs[4], wofs[4];
    bool okxy[4], site[4];
#pragma unroll
    for (int k = 0; k < 4; ++k) {
        int u = tid + 256 * k;
        int y = u / HX, x = u - y * HX;
        site[k] = (u < NSITE);
        int gy = y0 + y, gx = x0 + x;
        okxy[k] = site[k] & ((unsigned)gy < (unsigned)DIM) & ((unsigned)gx < (unsigned)DIM);
        gofs[k] = gy * DIM + gx;
        wofs[k] = y * HXP + x;
    }

    // ---- y-conv task (tid<80): output rows 2*ytp, 2*ytp+1, quad qx ----
    const int ytp = tid / 10, qx = tid - ytp * 10;
    const int ybase = (2 * ytp) * HXP + 4 * qx;
    // ---- x-conv pair: outputs cx = 2jp, 2jp+1 ----
    const int cy = tid >> 4, jp = tid & 15;
    const int xread = cy * HXP + 2 * jp;

    const __half2 hz = __float2half2_rn(0.f);
    __half2 accz[5][7];
#pragma unroll
    for (int c = 0; c < 5; ++c)
#pragma unroll
        for (int j = 0; j < 7; ++j) accz[c][j] = hz;

    float lsum = 0.f;
    float rp[4], rt[4];

    // ---- prologue: zero pad cols once, load+store slice 0 (zs = z0-3) ----
    if (tid < HY * 2) {
        int y = tid >> 1, c = tid & 1;
        sP[y * HXP + HX + c] = 0.f;
        sT[y * HXP + HX + c] = 0.f;
    }
    {
        int zs = z0 - 3;
        bool zok = ((unsigned)zs < (unsigned)DIM);
        int gz = base + zs * DIM2;
#pragma unroll
        for (int k = 0; k < 4; ++k) {
            rp[k] = 0.f; rt[k] = 0.f;
            if (zok && okxy[k]) { int gi = gz + gofs[k]; rp[k] = P[gi]; rt[k] = T[gi]; }
        }
#pragma unroll
        for (int k = 0; k < 4; ++k)
            if (site[k]) { sP[wofs[k]] = rp[k]; sT[wofs[k]] = rt[k]; }
    }
    __syncthreads();

    for (int i = 0; i < NSL; ++i) {
        // ---- issue next-slice global loads early (latency hides under conv) ----
        const bool have_next = (i + 1 < NSL);
        if (have_next) {
            int zs = z0 - 2 + i;
            bool zok = ((unsigned)zs < (unsigned)DIM);
            int gz = base + zs * DIM2;
#pragma unroll
            for (int k = 0; k < 4; ++k) {
                rp[k] = 0.f; rt[k] = 0.f;
                if (zok && okxy[k]) { int gi = gz + gofs[k]; rp[k] = P[gi]; rt[k] = T[gi]; }
            }
        }

        // ---- y-conv: vertical-2 float4 tasks (80 threads) ----
        if (tid < 80) {
            float A[5][4], B[5][4];
#pragma unroll
            for (int c = 0; c < 5; ++c)
#pragma unroll
                for (int e = 0; e < 4; ++e) { A[c][e] = 0.f; B[c][e] = 0.f; }
#pragma unroll
            for (int k = 0; k < 8; ++k) {
                float4 p4 = *(const float4*)&sP[ybase + k * HXP];
                float4 t4 = *(const float4*)&sT[ybase + k * HXP];
                float pe[4] = {p4.x, p4.y, p4.z, p4.w};
                float te[4] = {t4.x, t4.y, t4.z, t4.w};
#pragma unroll
                for (int e = 0; e < 4; ++e) {
                    float p = pe[e], t = te[e];
                    float pp = p * p, tt = t * t, pt = p * t;
                    if (k < 7) {
                        float w = Wk[k];
                        A[0][e] = fmaf(w, p,  A[0][e]);
                        A[1][e] = fmaf(w, t,  A[1][e]);
                        A[2][e] = fmaf(w, pp, A[2][e]);
                        A[3][e] = fmaf(w, tt, A[3][e]);
                        A[4][e] = fmaf(w, pt, A[4][e]);
                    }
                    if (k >= 1) {
                        float w = Wk[k - 1];
                        B[0][e] = fmaf(w, p,  B[0][e]);
                        B[1][e] = fmaf(w, t,  B[1][e]);
                        B[2][e] = fmaf(w, pp, B[2][e]);
                        B[3][e] = fmaf(w, tt, B[3][e]);
                        B[4][e] = fmaf(w, pt, B[4][e]);
                    }
                }
            }
#pragma unroll
            for (int c = 0; c < 5; ++c) {
                *(float4*)&yc[c * COFF + ybase]       = make_float4(A[c][0], A[c][1], A[c][2], A[c][3]);
                *(float4*)&yc[c * COFF + ybase + HXP] = make_float4(B[c][0], B[c][1], B[c][2], B[c][3]);
            }
        }
        __syncthreads();

        // ---- x-conv: 8-float window [2jp .. 2jp+7], 2 outputs ----
        float s0[5], s1[5];
#pragma unroll
        for (int c = 0; c < 5; ++c) {
            const float* yp = &yc[c * COFF + xread];
            float2 v0 = *(const float2*)(yp);
            float2 v1 = *(const float2*)(yp + 2);
            float2 v2 = *(const float2*)(yp + 4);
            float2 v3 = *(const float2*)(yp + 6);
            float v[8] = {v0.x, v0.y, v1.x, v1.y, v2.x, v2.y, v3.x, v3.y};
            float o0 = 0.f, o1 = 0.f;
#pragma unroll
            for (int k = 0; k < 7; ++k) {
                o0 = fmaf(Wk[k], v[k],     o0);
                o1 = fmaf(Wk[k], v[k + 1], o1);
            }
            s0[c] = o0; s1[c] = o1;
        }

        // ---- z scatter (packed fp16, voxel pair per lane) ----
#pragma unroll
        for (int c = 0; c < 5; ++c) {
            __half2 sp = __floats2half2_rn(s0[c], s1[c]);
#pragma unroll
            for (int j = 0; j < 7; ++j)
                accz[c][j] = __hfma2(__float2half2_rn(Wk[6 - j]), sp, accz[c][j]);
        }

        if (i >= 6) {
            float mp  = __low2float(accz[0][0]),  mt  = __low2float(accz[1][0]);
            float ep2 = __low2float(accz[2][0]),  et2 = __low2float(accz[3][0]);
            float ept = __low2float(accz[4][0]);
            float mp2 = mp * mp, mt2 = mt * mt, mpt = mp * mt;
            float num = fmaf(2.f, mpt, 1e-4f) * fmaf(2.f, ept - mpt, 9e-4f);
            float den = (mp2 + mt2 + 1e-4f) * ((ep2 - mp2) + (et2 - mt2) + 9e-4f);
            lsum += num * __builtin_amdgcn_rcpf(den);

            mp  = __high2float(accz[0][0]);  mt  = __high2float(accz[1][0]);
            ep2 = __high2float(accz[2][0]);  et2 = __high2float(accz[3][0]);
            ept = __high2float(accz[4][0]);
            mp2 = mp * mp; mt2 = mt * mt; mpt = mp * mt;
            num = fmaf(2.f, mpt, 1e-4f) * fmaf(2.f, ept - mpt, 9e-4f);
            den = (mp2 + mt2 + 1e-4f) * ((ep2 - mp2) + (et2 - mt2) + 9e-4f);
            lsum += num * __builtin_amdgcn_rcpf(den);
        }

        // ---- shift z pipeline ----
#pragma unroll
        for (int c = 0; c < 5; ++c) {
#pragma unroll
            for (int j = 0; j < 6; ++j) accz[c][j] = accz[c][j + 1];
            accz[c][6] = hz;
        }

        // ---- commit next slice to LDS ----
        if (have_next) {
#pragma unroll
            for (int k = 0; k < 4; ++k)
                if (site[k]) { sP[wofs[k]] = rp[k]; sT[wofs[k]] = rt[k]; }
        }
        __syncthreads();
    }

    // ---- block reduction, one f64 atomic ----
#pragma unroll
    for (int off = 32; off > 0; off >>= 1) lsum += __shfl_down(lsum, off);
    if ((tid & 63) == 0) red[tid >> 6] = lsum;
    __syncthreads();
    if (tid == 0) atomicAdd(acc, (double)(red[0] + red[1] + red[2] + red[3]));
}

__global__ void ssim_finalize(const double* __restrict__ acc, float* __restrict__ out) {
    if (threadIdx.x == 0 && blockIdx.x == 0)
        out[0] = 1.f - (float)(acc[0] / NVOX_D);
}

extern "C" void kernel_launch(void* const* d_in, const int* in_sizes, int n_in,
                              void* d_out, int out_size, void* d_ws, size_t ws_size,
                              hipStream_t stream) {
    const float* P = (const float*)d_in[0];
    const float* T = (const float*)d_in[1];
    float* out = (float*)d_out;
    double* acc = (double*)d_ws;

    ssim_zero_acc<<<1, 64, 0, stream>>>(acc);
    ssim_main<<<4 * 8 * 10 * 5, 256, 0, stream>>>(P, T, acc);
    ssim_finalize<<<1, 64, 0, stream>>>(acc, out);
}

// Round 4
// 123.668 us; speedup vs baseline: 2.1420x; 2.1420x over previous
//
#include <hip/hip_runtime.h>
#include <hip/hip_fp16.h>

#define DIM   160
#define DIM2  25600
#define TY    16
#define TX    32
#define TZ    32
#define HY    22            // TY + 6
#define HX    38            // TX + 6
#define NSL   38            // TZ + 6
#define NSITE (HY * HX)     // 836
#define YCC   (TY * HX)     // 608 floats per channel
#define NVOX_D 16384000.0

#define W0 0.03663285f
#define W1 0.11128076f
#define W2 0.21674532f
#define W3 0.27068213f

__global__ void ssim_zero_acc(double* acc) {
    if (threadIdx.x == 0 && blockIdx.x == 0) acc[0] = 0.0;
}

__global__ __launch_bounds__(256, 4) void ssim_main(const float* __restrict__ P,
                                                    const float* __restrict__ T,
                                                    double* __restrict__ acc) {
    const float Wk[7] = {W0, W1, W2, W3, W2, W1, W0};

    __shared__ float sP[2 * NSITE];
    __shared__ float sT[2 * NSITE];
    __shared__ float yc[5 * YCC];
    __shared__ float red[4];

    const int tid = threadIdx.x;
    int bid = blockIdx.x;
    int b  = bid / 250;  int r  = bid - b * 250;   // 5 zc * 10 ty * 5 tx
    int zc = r / 50;     int r2 = r - zc * 50;
    int ty = r2 / 5;     int tx = r2 - ty * 5;

    const int base = b * (DIM * DIM * DIM);
    const int z0 = zc * TZ, y0 = ty * TY - 3, x0 = tx * TX - 3;

    // ---- hoisted per-thread load sites (u = tid + 256k) ----
    int  gofs[4];
    bool ld[4], site[4];
#pragma unroll
    for (int k = 0; k < 4; ++k) {
        int u = tid + 256 * k;
        int y = u / HX, x = u - y * HX;
        site[k] = (u < NSITE);
        int gy = y0 + y, gx = x0 + x;
        ld[k] = site[k] & ((unsigned)gy < (unsigned)DIM) & ((unsigned)gx < (unsigned)DIM);
        gofs[k] = gy * DIM + gx;
    }

    // ---- y-conv vertical-pair tasks: task t -> rows 2r,2r+1, col x ----
    const int rA    = tid / HX;
    const int baseA = tid + HX * rA;          // halo offset of row 2rA, col x
    const bool hasB = (tid >= 208);           // tasks 256..303 on wave 3
    const int tB    = tid + 48;
    const int rB    = tB / HX;
    const int baseB = tB + HX * rB;

    // ---- x-conv: outputs (y=cy, x=2jp,2jp+1) ----
    const int xbase = (tid >> 4) * HX + 2 * (tid & 15);

    const __half2 hz = __float2half2_rn(0.f);
    __half2 az[5][7];
#pragma unroll
    for (int c = 0; c < 5; ++c)
#pragma unroll
        for (int j = 0; j < 7; ++j) az[c][j] = hz;

    float lsum = 0.f;
    float rp[4], rt[4];

    // ---- prologue: slice zs = z0-3 into buffer 0 ----
    {
        int zs = z0 - 3;
        bool zok = (unsigned)zs < (unsigned)DIM;
        const float* Pp = P + base + zs * DIM2;
        const float* Tp = T + base + zs * DIM2;
#pragma unroll
        for (int k = 0; k < 4; ++k) {
            rp[k] = 0.f; rt[k] = 0.f;
            if (zok && ld[k]) { rp[k] = Pp[gofs[k]]; rt[k] = Tp[gofs[k]]; }
        }
#pragma unroll
        for (int k = 0; k < 4; ++k)
            if (site[k]) { sP[tid + 256 * k] = rp[k]; sT[tid + 256 * k] = rt[k]; }
    }
    __syncthreads();

    for (int i = 0; i < NSL; ++i) {
        const float* cP = sP + (i & 1) * NSITE;
        const float* cT = sT + (i & 1) * NSITE;
        const bool hn = (i + 1 < NSL);

        // ---- prefetch next slice into regs (latency hides under y-conv) ----
        if (hn) {
            int zs = z0 + i - 2;
            bool zok = (unsigned)zs < (unsigned)DIM;
            const float* Pp = P + base + zs * DIM2;
            const float* Tp = T + base + zs * DIM2;
#pragma unroll
            for (int k = 0; k < 4; ++k) {
                rp[k] = 0.f; rt[k] = 0.f;
                if (zok && ld[k]) { rp[k] = Pp[gofs[k]]; rt[k] = Tp[gofs[k]]; }
            }
        }

        // ---- y-conv: vertical pair, shared products ----
        {
            const float* pp = cP + baseA;
            const float* qq = cT + baseA;
            float A0 = 0.f, A1 = 0.f, A2 = 0.f, A3 = 0.f, A4 = 0.f;
            float B0 = 0.f, B1 = 0.f, B2 = 0.f, B3 = 0.f, B4 = 0.f;
#pragma unroll
            for (int k = 0; k < 8; ++k) {
                float p = pp[HX * k], t = qq[HX * k];
                float p2 = p * p, t2 = t * t, pt = p * t;
                if (k < 7) {
                    float w = Wk[k];
                    A0 = fmaf(w, p, A0);  A1 = fmaf(w, t, A1);
                    A2 = fmaf(w, p2, A2); A3 = fmaf(w, t2, A3); A4 = fmaf(w, pt, A4);
                }
                if (k >= 1) {
                    float w = Wk[k - 1];
                    B0 = fmaf(w, p, B0);  B1 = fmaf(w, t, B1);
                    B2 = fmaf(w, p2, B2); B3 = fmaf(w, t2, B3); B4 = fmaf(w, pt, B4);
                }
            }
            yc[baseA]               = A0; yc[baseA + HX]           = B0;
            yc[YCC + baseA]         = A1; yc[YCC + baseA + HX]     = B1;
            yc[2 * YCC + baseA]     = A2; yc[2 * YCC + baseA + HX] = B2;
            yc[3 * YCC + baseA]     = A3; yc[3 * YCC + baseA + HX] = B3;
            yc[4 * YCC + baseA]     = A4; yc[4 * YCC + baseA + HX] = B4;
        }
        if (hasB) {
            const float* pp = cP + baseB;
            const float* qq = cT + baseB;
            float A0 = 0.f, A1 = 0.f, A2 = 0.f, A3 = 0.f, A4 = 0.f;
            float B0 = 0.f, B1 = 0.f, B2 = 0.f, B3 = 0.f, B4 = 0.f;
#pragma unroll
            for (int k = 0; k < 8; ++k) {
                float p = pp[HX * k], t = qq[HX * k];
                float p2 = p * p, t2 = t * t, pt = p * t;
                if (k < 7) {
                    float w = Wk[k];
                    A0 = fmaf(w, p, A0);  A1 = fmaf(w, t, A1);
                    A2 = fmaf(w, p2, A2); A3 = fmaf(w, t2, A3); A4 = fmaf(w, pt, A4);
                }
                if (k >= 1) {
                    float w = Wk[k - 1];
                    B0 = fmaf(w, p, B0);  B1 = fmaf(w, t, B1);
                    B2 = fmaf(w, p2, B2); B3 = fmaf(w, t2, B3); B4 = fmaf(w, pt, B4);
                }
            }
            yc[baseB]               = A0; yc[baseB + HX]           = B0;
            yc[YCC + baseB]         = A1; yc[YCC + baseB + HX]     = B1;
            yc[2 * YCC + baseB]     = A2; yc[2 * YCC + baseB + HX] = B2;
            yc[3 * YCC + baseB]     = A3; yc[3 * YCC + baseB + HX] = B3;
            yc[4 * YCC + baseB]     = A4; yc[4 * YCC + baseB + HX] = B4;
        }
        __syncthreads();

        // ---- x-conv: window [2jp..2jp+7], 2 outputs per thread ----
        float s0[5], s1[5];
#pragma unroll
        for (int c = 0; c < 5; ++c) {
            const float* yp = &yc[c * YCC + xbase];
            float2 v0 = *(const float2*)(yp);
            float2 v1 = *(const float2*)(yp + 2);
            float2 v2 = *(const float2*)(yp + 4);
            float2 v3 = *(const float2*)(yp + 6);
            float v[8] = {v0.x, v0.y, v1.x, v1.y, v2.x, v2.y, v3.x, v3.y};
            float o0 = 0.f, o1 = 0.f;
#pragma unroll
            for (int k = 0; k < 7; ++k) {
                o0 = fmaf(Wk[k], v[k],     o0);
                o1 = fmaf(Wk[k], v[k + 1], o1);
            }
            s0[c] = o0; s1[c] = o1;
        }

        // ---- z scatter (packed fp16 voxel pair) ----
#pragma unroll
        for (int c = 0; c < 5; ++c) {
            __half2 sp = __floats2half2_rn(s0[c], s1[c]);
#pragma unroll
            for (int j = 0; j < 7; ++j)
                az[c][j] = __hfma2(__float2half2_rn(Wk[6 - j]), sp, az[c][j]);
        }

        if (i >= 6) {
            float mp  = __low2float(az[0][0]),  mt  = __low2float(az[1][0]);
            float ep2 = __low2float(az[2][0]),  et2 = __low2float(az[3][0]);
            float ept = __low2float(az[4][0]);
            float mp2 = mp * mp, mt2 = mt * mt, mpt = mp * mt;
            float num = fmaf(2.f, mpt, 1e-4f) * fmaf(2.f, ept - mpt, 9e-4f);
            float den = (mp2 + mt2 + 1e-4f) * ((ep2 - mp2) + (et2 - mt2) + 9e-4f);
            lsum += num * __builtin_amdgcn_rcpf(den);

            mp  = __high2float(az[0][0]);  mt  = __high2float(az[1][0]);
            ep2 = __high2float(az[2][0]);  et2 = __high2float(az[3][0]);
            ept = __high2float(az[4][0]);
            mp2 = mp * mp; mt2 = mt * mt; mpt = mp * mt;
            num = fmaf(2.f, mpt, 1e-4f) * fmaf(2.f, ept - mpt, 9e-4f);
            den = (mp2 + mt2 + 1e-4f) * ((ep2 - mp2) + (et2 - mt2) + 9e-4f);
            lsum += num * __builtin_amdgcn_rcpf(den);
        }

        // ---- shift z pipeline ----
#pragma unroll
        for (int c = 0; c < 5; ++c) {
#pragma unroll
            for (int j = 0; j < 6; ++j) az[c][j] = az[c][j + 1];
            az[c][6] = hz;
        }

        // ---- commit next slice ----
        if (hn) {
            float* nP = sP + ((i + 1) & 1) * NSITE;
            float* nT = sT + ((i + 1) & 1) * NSITE;
#pragma unroll
            for (int k = 0; k < 4; ++k)
                if (site[k]) { nP[tid + 256 * k] = rp[k]; nT[tid + 256 * k] = rt[k]; }
        }
        __syncthreads();
    }

    // ---- block reduction, one f64 atomic ----
#pragma unroll
    for (int off = 32; off > 0; off >>= 1) lsum += __shfl_down(lsum, off);
    if ((tid & 63) == 0) red[tid >> 6] = lsum;
    __syncthreads();
    if (tid == 0) atomicAdd(acc, (double)(red[0] + red[1] + red[2] + red[3]));
}

__global__ void ssim_finalize(const double* __restrict__ acc, float* __restrict__ out) {
    if (threadIdx.x == 0 && blockIdx.x == 0)
        out[0] = 1.f - (float)(acc[0] / NVOX_D);
}

extern "C" void kernel_launch(void* const* d_in, const int* in_sizes, int n_in,
                              void* d_out, int out_size, void* d_ws, size_t ws_size,
                              hipStream_t stream) {
    const float* P = (const float*)d_in[0];
    const float* T = (const float*)d_in[1];
    float* out = (float*)d_out;
    double* acc = (double*)d_ws;

    ssim_zero_acc<<<1, 64, 0, stream>>>(acc);
    ssim_main<<<4 * 5 * 10 * 5, 256, 0, stream>>>(P, T, acc);
    ssim_finalize<<<1, 64, 0, stream>>>(acc, out);
}